// Round 4
// baseline (74.584 us; speedup 1.0000x reference)
//
#include <hip/hip_runtime.h>

typedef __attribute__((ext_vector_type(8))) short short8;
typedef __attribute__((ext_vector_type(4))) float f32x4;
typedef unsigned short ushort_t;

constexpr int N = 16384;
constexpr int K = 1024;
constexpr int M = 1024;

#define WAITVM(n) asm volatile("s_waitcnt vmcnt(" #n ")" ::: "memory")
#define FENCE() asm volatile("" ::: "memory")
#define BAR()                          \
    do {                               \
        FENCE();                       \
        __builtin_amdgcn_s_barrier();  \
        FENCE();                       \
    } while (0)

__device__ inline ushort_t f32_to_bf16(float f) {
    unsigned u = __builtin_bit_cast(unsigned, f);
    unsigned r = (u + 0x7fffu + ((u >> 16) & 1u)) >> 16;
    return (ushort_t)r;
}

__device__ inline void gload_lds16(const ushort_t* g, ushort_t* l) {
    __builtin_amdgcn_global_load_lds(
        (const __attribute__((address_space(1))) unsigned int*)g,
        (__attribute__((address_space(3))) unsigned int*)l,
        16, 0, 0);
}

// One block per mu row: norm, W = mu_n*inv_std (bf16), mmh = -0.5*sum(mu_n^2*inv_std)
__global__ void prep_mu(const float* __restrict__ mu, const float* __restrict__ stdv,
                        ushort_t* __restrict__ Wb, float* __restrict__ mmh) {
    int m = blockIdx.x;
    int t = threadIdx.x;
    float4 v = ((const float4*)(mu + (size_t)m * K))[t];
    float4 s = ((const float4*)stdv)[t];
    float ix = 1.0f / s.x, iy = 1.0f / s.y, iz = 1.0f / s.z, iw = 1.0f / s.w;
    float sum2  = v.x * v.x + v.y * v.y + v.z * v.z + v.w * v.w;
    float sum2w = v.x * v.x * ix + v.y * v.y * iy + v.z * v.z * iz + v.w * v.w * iw;
    for (int off = 32; off > 0; off >>= 1) {
        sum2  += __shfl_down(sum2, off, 64);
        sum2w += __shfl_down(sum2w, off, 64);
    }
    __shared__ float r2[4], r2w[4];
    __shared__ float s_scale;
    int lane = t & 63, w = t >> 6;
    if (lane == 0) { r2[w] = sum2; r2w[w] = sum2w; }
    __syncthreads();
    if (t == 0) {
        float tot2  = r2[0] + r2[1] + r2[2] + r2[3];
        float tot2w = r2w[0] + r2w[1] + r2w[2] + r2w[3];
        mmh[m] = -0.5f * tot2w / tot2;
        s_scale = rsqrtf(tot2);
    }
    __syncthreads();
    float sc = s_scale;
    ushort_t* wout = Wb + (size_t)m * K + t * 4;
    ushort_t tmp[4] = {f32_to_bf16(v.x * ix * sc), f32_to_bf16(v.y * iy * sc),
                       f32_to_bf16(v.z * iz * sc), f32_to_bf16(v.w * iw * sc)};
    *(uint2*)wout = *(const uint2*)tmp;
}

// Wave-per-row: x->bf16, xxh = -0.5*sum(x^2*inv_std). No barriers, no LDS.
__global__ __launch_bounds__(256) void prep_x(const float* __restrict__ x,
                                              const float* __restrict__ stdv,
                                              ushort_t* __restrict__ xb,
                                              float* __restrict__ xxh) {
    int row = blockIdx.x * 4 + (threadIdx.x >> 6);
    int lane = threadIdx.x & 63;
    const float4* src = (const float4*)(x + (size_t)row * K);
    const float4* sp  = (const float4*)stdv;
    uint2* dst = (uint2*)(xb + (size_t)row * K);
    float ssum = 0.f;
#pragma unroll
    for (int i = 0; i < 4; ++i) {
        int idx = lane + 64 * i;
        float4 v = src[idx];
        float4 s = sp[idx];
        ssum += v.x * v.x / s.x + v.y * v.y / s.y + v.z * v.z / s.z + v.w * v.w / s.w;
        ushort_t tmp[4] = {f32_to_bf16(v.x), f32_to_bf16(v.y),
                           f32_to_bf16(v.z), f32_to_bf16(v.w)};
        dst[idx] = *(const uint2*)tmp;
    }
#pragma unroll
    for (int off = 32; off > 0; off >>= 1) ssum += __shfl_down(ssum, off, 64);
    if (lane == 0) xxh[row] = -0.5f * ssum;
}

// ---------------------------------------------------------------------------
// 256x256 tile, BK=64, 8 waves (2Mx4N), double-buffered 128 KiB LDS.
// 4-phase-per-K-tile schedule (T3), derived counted vmcnt (T4), setprio (T5),
// XOR swizzle via pre-swizzled source (T2), XCD block swizzle (T1).
// Phases (snake): (m0,n0) (m0,n1) (m1,n1) (m1,n0).
// Stage schedule: B(t+1)@ph1 into buf^1; A(t+2)@ph4 into buf; vmcnt(4)@ph4.
// Invariant at tile-t boundary: only A(t+1) (4 loads) outstanding.
// ---------------------------------------------------------------------------
#define BK 64
#define TILE_ELEMS (256 * BK)          // 16384 ushorts = 32 KiB per buffer

__global__ __launch_bounds__(512, 2) void gemm_ep(
    const ushort_t* __restrict__ A, const ushort_t* __restrict__ B,
    const float* __restrict__ xxh, const float* __restrict__ mmh,
    float* __restrict__ C) {
    __shared__ ushort_t Als[2 * TILE_ELEMS];   // 64 KiB
    __shared__ ushort_t Bls[2 * TILE_ELEMS];   // 64 KiB

    int t = threadIdx.x;
    int lane = t & 63;
    int wave = t >> 6;
    int wr = wave >> 2;          // 0..1 (M half)
    int wc = wave & 3;           // 0..3 (N quarter)
    int r  = lane & 15;
    int lk = lane >> 4;

    // T1: XCD swizzle. nwg=256 = 8 XCDs x 32 (bijective: 256%8==0).
    int bid = blockIdx.x;
    int s = (bid & 7) * 32 + (bid >> 3);
    int tm = s >> 6;             // 0..3   (M/256)
    int tn = s & 63;             // 0..63  (N/256)

    const ushort_t* Abase = A + (size_t)tn * 256 * K;
    const ushort_t* Bbase = B + (size_t)tm * 256 * K;

    f32x4 acc[8][4] = {};
    short8 af[4][2];             // current m-half: 4 mi x 2 ks
    short8 bf[2][2];             // current n-half: 2 ni x 2 ks

    // Stage one matrix tile (all 256 rows x BK): 4 gload_lds per thread.
    // chunk c: lds row=c>>3, slot=c&7; source slot pre-swizzled (rule 21).
#define STAGE_MAT(Gb_, Lb_, kt_)                                               \
    {                                                                          \
        const ushort_t* g_ = (Gb_) + (size_t)(kt_) * BK;                       \
        ushort_t* l_ = (Lb_);                                                  \
        _Pragma("unroll")                                                      \
        for (int i_ = 0; i_ < 4; ++i_) {                                       \
            int c_ = i_ * 512 + t;                                             \
            int row_ = c_ >> 3;                                                \
            int slot_ = (c_ & 7) ^ (row_ & 7);                                 \
            gload_lds16(g_ + (size_t)row_ * K + slot_ * 8,                     \
                        l_ + (i_ * 512 + (wave << 6)) * 8);                    \
        }                                                                      \
    }

    // swizzled LDS element offset for fragment (row, ks):
    //   (row<<6) + ((lk ^ (row&7) ^ (ks<<2)) << 3); here row&7 == r&7.
#define LOAD_AF(As_, mh_)                                                      \
    _Pragma("unroll")                                                          \
    for (int mi_ = 0; mi_ < 4; ++mi_)                                          \
        _Pragma("unroll")                                                      \
        for (int ks_ = 0; ks_ < 2; ++ks_)                                      \
            af[mi_][ks_] = *(const short8*)&(As_)[                             \
                ((wr * 128 + (mh_) * 64 + mi_ * 16 + r) << 6) +                \
                ((lk ^ (r & 7) ^ (ks_ << 2)) << 3)];

#define LOAD_BF(Bs_, nh_)                                                      \
    _Pragma("unroll")                                                          \
    for (int ni_ = 0; ni_ < 2; ++ni_)                                          \
        _Pragma("unroll")                                                      \
        for (int ks_ = 0; ks_ < 2; ++ks_)                                      \
            bf[ni_][ks_] = *(const short8*)&(Bs_)[                             \
                ((wc * 64 + (nh_) * 32 + ni_ * 16 + r) << 6) +                 \
                ((lk ^ (r & 7) ^ (ks_ << 2)) << 3)];

#define MFMA_Q(mh_, nh_)                                                       \
    __builtin_amdgcn_s_setprio(1);                                             \
    _Pragma("unroll")                                                          \
    for (int mi_ = 0; mi_ < 4; ++mi_)                                          \
        _Pragma("unroll")                                                      \
        for (int ni_ = 0; ni_ < 2; ++ni_)                                      \
            _Pragma("unroll")                                                  \
            for (int ks_ = 0; ks_ < 2; ++ks_)                                  \
                acc[(mh_) * 4 + mi_][(nh_) * 2 + ni_] =                        \
                    __builtin_amdgcn_mfma_f32_16x16x32_bf16(                   \
                        af[mi_][ks_], bf[ni_][ks_],                            \
                        acc[(mh_) * 4 + mi_][(nh_) * 2 + ni_], 0, 0, 0);       \
    __builtin_amdgcn_s_setprio(0);

    // ---- prologue: A(0),B(0) -> buf0; A(1) -> buf1; wait A0+B0 landed.
    STAGE_MAT(Abase, Als, 0);
    STAGE_MAT(Bbase, Bls, 0);
    STAGE_MAT(Abase, Als + TILE_ELEMS, 1);
    WAITVM(4);
    BAR();

    const int NT = K / BK;            // 16 K-tiles
    for (int kt = 0; kt < NT; ++kt) {
        int cur = kt & 1;
        const ushort_t* As = Als + cur * TILE_ELEMS;
        const ushort_t* Bs = Bls + cur * TILE_ELEMS;
        ushort_t* AlsN = Als + (cur ^ 1) * TILE_ELEMS;
        ushort_t* BlsN = Bls + (cur ^ 1) * TILE_ELEMS;

        // ---- phase 1: quadrant (m0, n0); stage B(t+1) into buf^1
        LOAD_AF(As, 0);
        LOAD_BF(Bs, 0);
        if (kt + 1 < NT) STAGE_MAT(Bbase, BlsN, kt + 1);
        BAR();
        MFMA_Q(0, 0);
        BAR();

        // ---- phase 2: quadrant (m0, n1)
        LOAD_BF(Bs, 1);
        BAR();
        MFMA_Q(0, 1);
        BAR();

        // ---- phase 3: quadrant (m1, n1)
        LOAD_AF(As, 1);
        BAR();
        MFMA_Q(1, 1);
        BAR();

        // ---- phase 4: quadrant (m1, n0); stage A(t+2) into buf (A(t) dead)
        LOAD_BF(Bs, 0);
        if (kt + 2 < NT) STAGE_MAT(Abase, Als + cur * TILE_ELEMS, kt + 2);
        BAR();
        MFMA_Q(1, 0);
        // derived wait: retire A(t+1)+B(t+1); keep A(t+2) in flight.
        if (kt + 2 < NT) {
            WAITVM(4);
        } else if (kt + 1 < NT) {
            WAITVM(0);               // tail: drain A(NT-1)+B(NT-1)
        }
        BAR();
    }

    // epilogue: C[row][col] = acc + xxh[row] + mmh[col]
    int rowb = tn * 256 + wr * 128;
    int colb = tm * 256 + wc * 64;
#pragma unroll
    for (int mi = 0; mi < 8; ++mi) {
        float xh[4];
#pragma unroll
        for (int j = 0; j < 4; ++j) xh[j] = xxh[rowb + mi * 16 + lk * 4 + j];
#pragma unroll
        for (int ni = 0; ni < 4; ++ni) {
            int col = colb + ni * 16 + r;
            float mh = mmh[col];
#pragma unroll
            for (int j = 0; j < 4; ++j) {
                int row = rowb + mi * 16 + lk * 4 + j;
                C[(size_t)row * M + col] = acc[mi][ni][j] + xh[j] + mh;
            }
        }
    }
#undef STAGE_MAT
#undef LOAD_AF
#undef LOAD_BF
#undef MFMA_Q
}

extern "C" void kernel_launch(void* const* d_in, const int* in_sizes, int n_in,
                              void* d_out, int out_size, void* d_ws, size_t ws_size,
                              hipStream_t stream) {
    const float* x    = (const float*)d_in[0];
    const float* mu   = (const float*)d_in[1];
    const float* stdv = (const float*)d_in[2];
    float* out = (float*)d_out;

    char* ws = (char*)d_ws;
    ushort_t* xb  = (ushort_t*)ws;                                  // N*K*2 = 32 MB
    ushort_t* Wb  = (ushort_t*)(ws + (size_t)N * K * 2);            // M*K*2 = 2 MB
    float*    xxh = (float*)(ws + (size_t)N * K * 2 + (size_t)M * K * 2);
    float*    mmh = (float*)((char*)xxh + (size_t)N * sizeof(float));

    prep_mu<<<M, 256, 0, stream>>>(mu, stdv, Wb, mmh);
    prep_x<<<N / 4, 256, 0, stream>>>(x, stdv, xb, xxh);
    gemm_ep<<<(N / 256) * (M / 256), 512, 0, stream>>>(xb, Wb, xxh, mmh, out);
}

// Round 5
// 49.800 us; speedup vs baseline: 1.4977x; 1.4977x over previous
//
#include <hip/hip_runtime.h>

typedef __attribute__((ext_vector_type(8))) int   i32x8;
typedef __attribute__((ext_vector_type(4))) float f32x4;
typedef unsigned int uint32;

constexpr int N = 16384;
constexpr int K = 1024;
constexpr int M = 1024;

#define WAITVM(n) asm volatile("s_waitcnt vmcnt(" #n ")" ::: "memory")
#define FENCE() asm volatile("" ::: "memory")
#define BAR()                          \
    do {                               \
        FENCE();                       \
        __builtin_amdgcn_s_barrier();  \
        FENCE();                       \
    } while (0)

__device__ inline void gload_lds16(const unsigned char* g, unsigned char* l) {
    __builtin_amdgcn_global_load_lds(
        (const __attribute__((address_space(1))) unsigned int*)g,
        (__attribute__((address_space(3))) unsigned int*)l,
        16, 0, 0);
}

// pack 4 f32 -> 4 OCP e4m3 bytes (k-ascending), saturating
__device__ inline uint32 pack4_fp8(float a, float b, float c, float d) {
    int v = __builtin_amdgcn_cvt_pk_fp8_f32(a, b, 0, false);   // bytes 0,1
    v = __builtin_amdgcn_cvt_pk_fp8_f32(c, d, v, true);        // bytes 2,3
    return (uint32)v;
}

// One block per mu row: norm; W8 = mu_n*inv_std*0.25 (fp8); mmh = -0.5*sum(mu_n^2*inv_std)
__global__ void prep_mu(const float* __restrict__ mu, const float* __restrict__ stdv,
                        uint32* __restrict__ Wb8, float* __restrict__ mmh) {
    int m = blockIdx.x;
    int t = threadIdx.x;
    float4 v = ((const float4*)(mu + (size_t)m * K))[t];
    float4 s = ((const float4*)stdv)[t];
    float ix = 1.0f / s.x, iy = 1.0f / s.y, iz = 1.0f / s.z, iw = 1.0f / s.w;
    float sum2  = v.x * v.x + v.y * v.y + v.z * v.z + v.w * v.w;
    float sum2w = v.x * v.x * ix + v.y * v.y * iy + v.z * v.z * iz + v.w * v.w * iw;
    for (int off = 32; off > 0; off >>= 1) {
        sum2  += __shfl_down(sum2, off, 64);
        sum2w += __shfl_down(sum2w, off, 64);
    }
    __shared__ float r2[4], r2w[4];
    __shared__ float s_scale;
    int lane = t & 63, w = t >> 6;
    if (lane == 0) { r2[w] = sum2; r2w[w] = sum2w; }
    __syncthreads();
    if (t == 0) {
        float tot2  = r2[0] + r2[1] + r2[2] + r2[3];
        float tot2w = r2w[0] + r2w[1] + r2w[2] + r2w[3];
        mmh[m] = -0.5f * tot2w / tot2;
        s_scale = rsqrtf(tot2) * 0.25f;        // fold the 1/4 fp8-range scale
    }
    __syncthreads();
    float sc = s_scale;
    Wb8[m * (K / 4) + t] = pack4_fp8(v.x * ix * sc, v.y * iy * sc,
                                     v.z * iz * sc, v.w * iw * sc);
}

// Wave-per-row: x->fp8, xxh = -0.5*sum(x^2*inv_std). No barriers, no LDS.
__global__ __launch_bounds__(256) void prep_x(const float* __restrict__ x,
                                              const float* __restrict__ stdv,
                                              uint32* __restrict__ xb8,
                                              float* __restrict__ xxh) {
    int row = blockIdx.x * 4 + (threadIdx.x >> 6);
    int lane = threadIdx.x & 63;
    const float4* src = (const float4*)(x + (size_t)row * K);
    const float4* sp  = (const float4*)stdv;
    uint32* dst = xb8 + (size_t)row * (K / 4);
    float ssum = 0.f;
#pragma unroll
    for (int i = 0; i < 4; ++i) {
        int idx = lane + 64 * i;
        float4 v = src[idx];
        float4 s = sp[idx];
        ssum += v.x * v.x / s.x + v.y * v.y / s.y + v.z * v.z / s.z + v.w * v.w / s.w;
        dst[idx] = pack4_fp8(v.x, v.y, v.z, v.w);
    }
#pragma unroll
    for (int off = 32; off > 0; off >>= 1) ssum += __shfl_down(ssum, off, 64);
    if (lane == 0) xxh[row] = -0.5f * ssum;
}

// ---------------------------------------------------------------------------
// fp8-MX GEMM (uniform scale = 1.0): C = (A8 * B8^T)*4 + xxh[row] + mmh[col].
// 128x128 tile, BK=128 bytes (one mfma_scale_16x16x128 k-step), 4 waves 2x2,
// double-buffered 64 KiB LDS -> 2 blocks/CU (TLP hides the 2-barrier drain).
// Swizzle: 16B-slot ^= (row&7) via pre-swizzled source (rule 21).
// ---------------------------------------------------------------------------
#define BKB 128
#define TILEB (128 * BKB)              // 16 KiB per matrix per buffer

__global__ __launch_bounds__(256, 2) void gemm_ep(
    const unsigned char* __restrict__ A8, const unsigned char* __restrict__ B8,
    const float* __restrict__ xxh, const float* __restrict__ mmh,
    float* __restrict__ C) {
    __shared__ unsigned char Als[2 * TILEB];   // 32 KiB
    __shared__ unsigned char Bls[2 * TILEB];   // 32 KiB

    int t = threadIdx.x;
    int lane = t & 63;
    int wave = t >> 6;
    int wr = wave >> 1;          // 0..1
    int wc = wave & 1;           // 0..1
    int r  = lane & 15;
    int lk = lane >> 4;

    // T1: XCD swizzle, nwg=1024 (bijective: 1024%8==0)
    int bid = blockIdx.x;
    int swz = (bid & 7) * 128 + (bid >> 3);
    int tn = swz >> 3;           // 0..127
    int tm = swz & 7;            // 0..7

    const unsigned char* Abase = A8 + (size_t)tn * 128 * K;
    const unsigned char* Bbase = B8 + (size_t)tm * 128 * K;

    f32x4 acc[4][4] = {};

    // staging: per matrix-tile 1024 16B chunks (128 rows x 8 slots);
    // 256 threads -> 4 chunks each. LDS dest linear; source slot ^= row&7.
#define STAGE(kt_, buf_)                                                       \
    {                                                                          \
        const unsigned char* Ag_ = Abase + (size_t)(kt_)*BKB;                  \
        const unsigned char* Bg_ = Bbase + (size_t)(kt_)*BKB;                  \
        unsigned char* Al_ = Als + (buf_)*TILEB;                               \
        unsigned char* Bl_ = Bls + (buf_)*TILEB;                               \
        _Pragma("unroll")                                                      \
        for (int i_ = 0; i_ < 4; ++i_) {                                       \
            int c_ = i_ * 256 + t;                                             \
            int row_ = c_ >> 3;                                                \
            int gs_ = (c_ & 7) ^ (row_ & 7);                                   \
            gload_lds16(Ag_ + (size_t)row_ * K + gs_ * 16,                     \
                        Al_ + (i_ * 256 + wave * 64) * 16);                    \
        }                                                                      \
        _Pragma("unroll")                                                      \
        for (int i_ = 0; i_ < 4; ++i_) {                                       \
            int c_ = i_ * 256 + t;                                             \
            int row_ = c_ >> 3;                                                \
            int gs_ = (c_ & 7) ^ (row_ & 7);                                   \
            gload_lds16(Bg_ + (size_t)row_ * K + gs_ * 16,                     \
                        Bl_ + (i_ * 256 + wave * 64) * 16);                    \
        }                                                                      \
    }

    STAGE(0, 0);
    WAITVM(0);
    BAR();

    const int NT = K / BKB;           // 8 K-tiles
    for (int kt = 0; kt < NT; ++kt) {
        int cur = kt & 1;
        if (kt + 1 < NT) STAGE(kt + 1, cur ^ 1);   // 8 loads in flight over MFMA

        const unsigned char* As = Als + cur * TILEB;
        const unsigned char* Bs = Bls + cur * TILEB;

        // fragments: per lane 32B of row (wr*64+mi*16+r), k = lk*32 + [0,32)
        // swizzled slots: (lk*2+h) ^ (r&7)
        i32x8 af[4], bf[4];
#pragma unroll
        for (int mi = 0; mi < 4; ++mi) {
            int row = wr * 64 + mi * 16 + r;
            uint4 q0 = *(const uint4*)&As[row * BKB + (((lk << 1) | 0) ^ (r & 7)) * 16];
            uint4 q1 = *(const uint4*)&As[row * BKB + (((lk << 1) | 1) ^ (r & 7)) * 16];
            af[mi][0] = q0.x; af[mi][1] = q0.y; af[mi][2] = q0.z; af[mi][3] = q0.w;
            af[mi][4] = q1.x; af[mi][5] = q1.y; af[mi][6] = q1.z; af[mi][7] = q1.w;
        }
#pragma unroll
        for (int ni = 0; ni < 4; ++ni) {
            int row = wc * 64 + ni * 16 + r;
            uint4 q0 = *(const uint4*)&Bs[row * BKB + (((lk << 1) | 0) ^ (r & 7)) * 16];
            uint4 q1 = *(const uint4*)&Bs[row * BKB + (((lk << 1) | 1) ^ (r & 7)) * 16];
            bf[ni][0] = q0.x; bf[ni][1] = q0.y; bf[ni][2] = q0.z; bf[ni][3] = q0.w;
            bf[ni][4] = q1.x; bf[ni][5] = q1.y; bf[ni][6] = q1.z; bf[ni][7] = q1.w;
        }

        __builtin_amdgcn_s_setprio(1);
#pragma unroll
        for (int mi = 0; mi < 4; ++mi)
#pragma unroll
            for (int ni = 0; ni < 4; ++ni)
                acc[mi][ni] = __builtin_amdgcn_mfma_scale_f32_16x16x128_f8f6f4(
                    af[mi], bf[ni], acc[mi][ni],
                    0, 0,                       // cbsz=FP8(e4m3), blgp=FP8
                    0, 0x7f7f7f7f,              // scale_a sel, E8M0=127 -> 1.0
                    0, 0x7f7f7f7f);             // scale_b sel, 1.0
        __builtin_amdgcn_s_setprio(0);

        if (kt + 1 < NT) WAITVM(0);
        BAR();
    }

    // epilogue: C[row][col] = 4*acc + xxh[row] + mmh[col]
    int rowb = tn * 128 + wr * 64;
    int colb = tm * 128 + wc * 64;
#pragma unroll
    for (int mi = 0; mi < 4; ++mi) {
        float xh[4];
#pragma unroll
        for (int j = 0; j < 4; ++j) xh[j] = xxh[rowb + mi * 16 + lk * 4 + j];
#pragma unroll
        for (int ni = 0; ni < 4; ++ni) {
            int col = colb + ni * 16 + r;
            float mh = mmh[col];
#pragma unroll
            for (int j = 0; j < 4; ++j) {
                int row = rowb + mi * 16 + lk * 4 + j;
                C[(size_t)row * M + col] = acc[mi][ni][j] * 4.0f + xh[j] + mh;
            }
        }
    }
#undef STAGE
}

extern "C" void kernel_launch(void* const* d_in, const int* in_sizes, int n_in,
                              void* d_out, int out_size, void* d_ws, size_t ws_size,
                              hipStream_t stream) {
    const float* x    = (const float*)d_in[0];
    const float* mu   = (const float*)d_in[1];
    const float* stdv = (const float*)d_in[2];
    float* out = (float*)d_out;

    char* ws = (char*)d_ws;
    unsigned char* xb8 = (unsigned char*)ws;                        // N*K   = 16 MB
    unsigned char* Wb8 = (unsigned char*)(ws + (size_t)N * K);      // M*K   = 1 MB
    float* xxh = (float*)(ws + (size_t)N * K + (size_t)M * K);      // 64 KB
    float* mmh = (float*)((char*)xxh + (size_t)N * sizeof(float));  // 4 KB

    prep_mu<<<M, 256, 0, stream>>>(mu, stdv, (uint32*)Wb8, mmh);
    prep_x<<<N / 4, 256, 0, stream>>>(x, stdv, (uint32*)xb8, xxh);
    gemm_ep<<<(N / 128) * (M / 128), 256, 0, stream>>>(xb8, Wb8, xxh, mmh, out);
}